// Round 1
// baseline (4104.364 us; speedup 1.0000x reference)
//
#include <hip/hip_runtime.h>

// CYK net: L=64, B=32, DIN=D=FFS=512
// Restructured:
//   P[cell] = table[cell] @ WcL.T ; Q[cell] = table[cell] @ WcR.T
//   node(j,s) = bc + max_k ( P[j,j+k] + Q[j+k+1,j+s] )
//   vals = node @ W2.T + b2  -> table[j,j+s]
//   P[j,j+s] = node @ M_L.T + pbL ;  Q = node @ M_R.T + pbR   (M_L=WcL@W2 etc.)
// One GEMM per level: (32n x 512) @ BigB(512 x 1536) -> [vals | P | Q]

#define Lx 64
#define Bb 32
#define Dd 512
#define CELLSZ (Bb*Dd)          // 16384 floats per cell tile
#define NCELLS 2080

__device__ __forceinline__ int tri_idx(int a, int c) {
    return a*Lx - (a*(a-1))/2 + (c - a);
}

// ---------------- small setup kernels ----------------

__global__ void k_lengths(const float* __restrict__ xs_mask, float* __restrict__ lengths) {
    int b = threadIdx.x;
    if (b < Bb) {
        float s = 0.f;
        for (int i = 0; i < Lx; ++i) s += xs_mask[i*Bb + b];
        lengths[b] = s;
    }
}

__global__ void k_mask(const float* __restrict__ lengths, float* __restrict__ mask_out) {
    int idx = blockIdx.x*256 + threadIdx.x;     // L*L*B = 131072
    int b = idx & 31;
    int j = (idx >> 5) & 63;
    int i = idx >> 11;
    mask_out[idx] = (j >= i && (float)j < lengths[b]) ? 1.f : 0.f;
}

// biasBig = [ b2 | b2@WcL.T | b2@WcR.T ]  (1536)
__global__ void k_bias(const float* __restrict__ b2, const float* __restrict__ Wc,
                       float* __restrict__ biasBig) {
    int c = blockIdx.x*256 + threadIdx.x;
    if (c >= 1536) return;
    if (c < 512) { biasBig[c] = b2[c]; return; }
    int p = (c - 512) & 511;
    int dofs = (c < 1024) ? 0 : 512;
    float s = 0.f;
    for (int d = 0; d < 512; ++d) s += b2[d] * Wc[p*1024 + dofs + d];
    biasBig[c] = s;
}

// W1T[d][dd]=W1[dd][d];  BigB[f][dd]=W2[dd][f] (cols 0..511);  B0[d][c]: Wc transposed
__global__ void k_transposes(const float* __restrict__ W1, const float* __restrict__ W2,
                             const float* __restrict__ Wc,
                             float* __restrict__ W1T, float* __restrict__ BigB,
                             float* __restrict__ B0) {
    int gid = blockIdx.x*256 + threadIdx.x;
    if (gid < 262144) {
        int d = gid >> 9, dd = gid & 511;
        W1T[d*512 + dd] = W1[dd*512 + d];
    } else if (gid < 524288) {
        int e = gid - 262144;
        int f = e >> 9, dd = e & 511;
        BigB[f*1536 + dd] = W2[dd*512 + f];
    } else {
        int e = gid - 524288;
        int d = e >> 10, c = e & 1023;
        B0[d*1024 + c] = (c < 512) ? Wc[c*1024 + d] : Wc[(c-512)*1024 + 512 + d];
    }
}

// BigB[f][512+p] = sum_d Wc[p'][dofs+d] * W2[d][f]   (M_L^T and M_R^T)
__global__ void k_gemm_M(const float* __restrict__ W2, const float* __restrict__ Wc,
                         float* __restrict__ BigB) {
    __shared__ float W2s[32][33];
    __shared__ float Wcs[32][33];
    int ftile = blockIdx.x & 15;
    int ptile = blockIdx.x >> 4;          // 0..31 over p in [0,1024)
    int f0 = ftile*32, p0 = ptile*32;
    int dofs  = (p0 >= 512) ? 512 : 0;
    int prow0 = (p0 >= 512) ? (p0 - 512) : p0;
    int t = threadIdx.x;
    int ff = t & 31, pg = t >> 5;         // pg 0..7
    float acc[4] = {0,0,0,0};
    for (int d0 = 0; d0 < 512; d0 += 32) {
        __syncthreads();
        #pragma unroll
        for (int i = 0; i < 4; ++i) {
            int e = t + 256*i;
            int r = e >> 5, cc = e & 31;
            W2s[r][cc] = W2[(d0 + r)*512 + f0 + cc];
            Wcs[r][cc] = Wc[(prow0 + r)*1024 + dofs + d0 + cc];
        }
        __syncthreads();
        #pragma unroll
        for (int dd = 0; dd < 32; ++dd) {
            float w = W2s[dd][ff];
            #pragma unroll
            for (int ii = 0; ii < 4; ++ii)
                acc[ii] += w * Wcs[pg*4 + ii][dd];
        }
    }
    #pragma unroll
    for (int ii = 0; ii < 4; ++ii) {
        int p = p0 + pg*4 + ii;
        BigB[(f0 + ff)*1536 + 512 + p] = acc[ii];
    }
}

// ---------------- unified per-cell GEMM: (32 x 512) @ (512 x NCOLS) ----------------
// MODE 0: diag   A=xs_h[cell]          B=W1T  bias=b1      -> table[i,i]
// MODE 1: pq0    A=table[(i,i)]        B=B0   bias=null    -> P,Q of level-0 cells
// MODE 2: level  A=node[cell]          B=BigB bias=biasBig -> table[j,j+s], P, Q
template<int MODE, int NCOLS>
__global__ __launch_bounds__(256) void k_gemm(
    const float* __restrict__ Abase, const float* __restrict__ Bmat,
    const float* __restrict__ bias,
    float* __restrict__ table, float* __restrict__ P, float* __restrict__ Q, int s)
{
    constexpr int CTILES = NCOLS / 256;
    int cell = blockIdx.x / CTILES;
    int ct   = blockIdx.x % CTILES;
    int c0   = ct * 256;
    const float* A;
    if (MODE == 0)      A = Abase + cell*CELLSZ;
    else if (MODE == 1) A = Abase + (size_t)cell*65*CELLSZ;
    else                A = Abase + cell*CELLSZ;

    __shared__ float Ast[32][36];     // A transposed: Ast[kk][r]
    __shared__ float Bs[32][256];
    int t  = threadIdx.x;
    int tx = t & 63, ty = t >> 6;     // cols 4*tx, rows 8*ty
    float acc[8][4];
    #pragma unroll
    for (int i = 0; i < 8; ++i)
        #pragma unroll
        for (int j = 0; j < 4; ++j) acc[i][j] = 0.f;

    for (int k0 = 0; k0 < 512; k0 += 32) {
        __syncthreads();
        {   // stage A (32 rows x 32 k), transposed into LDS
            int r = t >> 3, c4 = t & 7;
            float4 v = *reinterpret_cast<const float4*>(&A[r*512 + k0 + 4*c4]);
            Ast[4*c4+0][r] = v.x; Ast[4*c4+1][r] = v.y;
            Ast[4*c4+2][r] = v.z; Ast[4*c4+3][r] = v.w;
        }
        {   // stage B (32 k x 256 cols)
            int c4 = t & 63;
            int kbase = t >> 6;
            #pragma unroll
            for (int p = 0; p < 8; ++p) {
                int kk = p*4 + kbase;
                float4 v = *reinterpret_cast<const float4*>(&Bmat[(size_t)(k0+kk)*NCOLS + c0 + 4*c4]);
                *reinterpret_cast<float4*>(&Bs[kk][4*c4]) = v;
            }
        }
        __syncthreads();
        #pragma unroll
        for (int kk = 0; kk < 32; ++kk) {
            float4 a0 = *reinterpret_cast<const float4*>(&Ast[kk][8*ty]);
            float4 a1 = *reinterpret_cast<const float4*>(&Ast[kk][8*ty+4]);
            float4 b  = *reinterpret_cast<const float4*>(&Bs[kk][4*tx]);
            float av[8] = {a0.x,a0.y,a0.z,a0.w,a1.x,a1.y,a1.z,a1.w};
            #pragma unroll
            for (int i = 0; i < 8; ++i) {
                acc[i][0] += av[i]*b.x; acc[i][1] += av[i]*b.y;
                acc[i][2] += av[i]*b.z; acc[i][3] += av[i]*b.w;
            }
        }
    }
    #pragma unroll
    for (int i = 0; i < 8; ++i) {
        int r = 8*ty + i;
        int C = c0 + 4*tx;
        float4 v = make_float4(acc[i][0],acc[i][1],acc[i][2],acc[i][3]);
        if (MODE != 1) { v.x += bias[C]; v.y += bias[C+1]; v.z += bias[C+2]; v.w += bias[C+3]; }
        float* dst;
        if (MODE == 0) {
            dst = table + (size_t)cell*65*CELLSZ + r*512 + C;
        } else if (MODE == 1) {
            int tc = tri_idx(cell, cell);
            dst = (C < 512) ? (P + (size_t)tc*CELLSZ + r*512 + C)
                            : (Q + (size_t)tc*CELLSZ + r*512 + (C - 512));
        } else {
            int tc = tri_idx(cell, cell) + s;
            if (C < 512)       dst = table + (size_t)(cell*64 + cell + s)*CELLSZ + r*512 + C;
            else if (C < 1024) dst = P + (size_t)tc*CELLSZ + r*512 + (C - 512);
            else               dst = Q + (size_t)tc*CELLSZ + r*512 + (C - 1024);
        }
        *reinterpret_cast<float4*>(dst) = v;
    }
}

// ---------------- node max-reduce ----------------
// block covers (cell j, f-block of 128, b-range BS); BS templated for tail levels
template<int BS>
__global__ __launch_bounds__(256) void k_node(const float* __restrict__ P,
                                              const float* __restrict__ Q,
                                              const float* __restrict__ bc,
                                              float* __restrict__ node, int s)
{
    constexpr int BPC = 4 * (32 / BS);          // blocks per cell
    constexpr int E = BS / 2;                   // elems per thread
    int j   = blockIdx.x / BPC;
    int sub = blockIdx.x % BPC;
    int fb = sub & 3, bh = sub >> 2;
    int t = threadIdx.x;
    int f = fb*128 + (t & 127);
    int b0 = bh*BS + (t >> 7);                  // + 2*e below
    float acc[E];
    #pragma unroll
    for (int e = 0; e < E; ++e) acc[e] = -3.402823466e38f;
    int basePt = tri_idx(j, j);
    for (int k = 0; k < s; ++k) {
        const float* Pp = P + (size_t)(basePt + k)*CELLSZ + f;
        int a = j + k + 1;
        int tQ = a*Lx - (a*(a-1))/2 + (j + s - a);
        const float* Qp = Q + (size_t)tQ*CELLSZ + f;
        #pragma unroll
        for (int e = 0; e < E; ++e) {
            int b = b0 + 2*e;
            float v = Pp[b*512] + Qp[b*512];
            acc[e] = fmaxf(acc[e], v);
        }
    }
    float bcv = bc[f];
    #pragma unroll
    for (int e = 0; e < E; ++e) {
        int b = b0 + 2*e;
        node[j*CELLSZ + b*512 + f] = acc[e] + bcv;
    }
}

// ---------------- launch ----------------

extern "C" void kernel_launch(void* const* d_in, const int* in_sizes, int n_in,
                              void* d_out, int out_size, void* d_ws, size_t ws_size,
                              hipStream_t stream) {
    const float* xs_h    = (const float*)d_in[0];
    const float* xs_mask = (const float*)d_in[1];
    const float* W1      = (const float*)d_in[2];
    const float* b1      = (const float*)d_in[3];
    const float* Wc      = (const float*)d_in[4];
    const float* bc      = (const float*)d_in[5];
    const float* W2      = (const float*)d_in[6];
    const float* b2      = (const float*)d_in[7];

    float* table   = (float*)d_out;                     // 64*64*32*512
    float* maskout = table + 67108864;                  // 64*64*32

    float* ws      = (float*)d_ws;
    float* P       = ws;                                // 2080*16384 = 34,078,720
    float* Q       = P + 34078720;
    float* node    = Q + 34078720;                      // 63*16384
    float* W1T     = node + 1032192;                    // 512*512
    float* B0      = W1T + 262144;                      // 512*1024
    float* BigB    = B0 + 524288;                       // 512*1536
    float* biasBig = BigB + 786432;                     // 1536
    float* lengths = biasBig + 1536;                    // 32

    hipMemsetAsync(table, 0, (size_t)67108864*4, stream);
    k_lengths<<<1, 64, 0, stream>>>(xs_mask, lengths);
    k_mask<<<512, 256, 0, stream>>>(lengths, maskout);
    k_transposes<<<4096, 256, 0, stream>>>(W1, W2, Wc, W1T, BigB, B0);
    k_gemm_M<<<512, 256, 0, stream>>>(W2, Wc, BigB);
    k_bias<<<6, 256, 0, stream>>>(b2, Wc, biasBig);

    // level 0: diag then P/Q projections
    k_gemm<0, 512><<<64*2, 256, 0, stream>>>(xs_h, W1T, b1, table, P, Q, 0);
    k_gemm<1, 1024><<<64*4, 256, 0, stream>>>(table, B0, nullptr, table, P, Q, 0);

    for (int s = 1; s < 64; ++s) {
        int n = 64 - s;
        if (n >= 16) k_node<16><<<n*8,  256, 0, stream>>>(P, Q, bc, node, s);
        else         k_node<2> <<<n*64, 256, 0, stream>>>(P, Q, bc, node, s);
        k_gemm<2, 1536><<<n*6, 256, 0, stream>>>(node, BigB, biasBig, table, P, Q, s);
    }
}

// Round 2
// 2495.652 us; speedup vs baseline: 1.6446x; 1.6446x over previous
//
#include <hip/hip_runtime.h>

// CYK net: L=64, B=32, DIN=D=FFS=512
//   P[cell] = table[cell] @ WcL.T ; Q[cell] = table[cell] @ WcR.T
//   node(j,s) = bc + max_k ( P[j,j+k] + Q[j+k+1,j+s] )
//   [vals|P|Q] = node @ BigB + biasBig   (one GEMM per level, bf16x3 MFMA)

#define Lx 64
#define Bb 32
#define Dd 512
#define CELLSZ (Bb*Dd)          // 16384 floats per cell tile
#define NCELLS 2080

typedef __attribute__((ext_vector_type(8))) short short8v;
typedef __attribute__((ext_vector_type(4))) float f32x4;

__device__ __forceinline__ int tri_idx(int a, int c) {
    return a*Lx - (a*(a-1))/2 + (c - a);
}

__device__ __forceinline__ unsigned short f2bf(float x) {
    unsigned u = __float_as_uint(x);
    unsigned r = (u + 0x7FFFu + ((u >> 16) & 1u)) >> 16;
    return (unsigned short)r;
}
__device__ __forceinline__ float bf2f(unsigned short h) {
    return __uint_as_float((unsigned)h << 16);
}

// ---------------- small setup kernels ----------------

__global__ void k_lengths(const float* __restrict__ xs_mask, float* __restrict__ lengths) {
    int b = threadIdx.x;
    if (b < Bb) {
        float s = 0.f;
        for (int i = 0; i < Lx; ++i) s += xs_mask[i*Bb + b];
        lengths[b] = s;
    }
}

__global__ void k_mask(const float* __restrict__ lengths, float* __restrict__ mask_out) {
    int idx = blockIdx.x*256 + threadIdx.x;     // L*L*B = 131072
    int b = idx & 31;
    int j = (idx >> 5) & 63;
    int i = idx >> 11;
    mask_out[idx] = (j >= i && (float)j < lengths[b]) ? 1.f : 0.f;
}

// biasBig = [ b2 | b2@WcL.T | b2@WcR.T ]  (1536)
__global__ void k_bias(const float* __restrict__ b2, const float* __restrict__ Wc,
                       float* __restrict__ biasBig) {
    int c = blockIdx.x*256 + threadIdx.x;
    if (c >= 1536) return;
    if (c < 512) { biasBig[c] = b2[c]; return; }
    int p = (c - 512) & 511;
    int dofs = (c < 1024) ? 0 : 512;
    float s = 0.f;
    for (int d = 0; d < 512; ++d) s += b2[d] * Wc[p*1024 + dofs + d];
    biasBig[c] = s;
}

// W1T[d][dd]=W1[dd][d];  BigB[k][c] c<512: W2[c][k];  B0[d][c]: Wc transposed
__global__ void k_transposes(const float* __restrict__ W1, const float* __restrict__ W2,
                             const float* __restrict__ Wc,
                             float* __restrict__ W1T, float* __restrict__ BigB,
                             float* __restrict__ B0) {
    int gid = blockIdx.x*256 + threadIdx.x;
    if (gid < 262144) {
        int d = gid >> 9, dd = gid & 511;
        W1T[d*512 + dd] = W1[dd*512 + d];
    } else if (gid < 524288) {
        int e = gid - 262144;
        int f = e >> 9, dd = e & 511;
        BigB[f*1536 + dd] = W2[dd*512 + f];
    } else {
        int e = gid - 524288;
        int d = e >> 10, c = e & 1023;
        B0[d*1024 + c] = (c < 512) ? Wc[c*1024 + d] : Wc[(c-512)*1024 + 512 + d];
    }
}

// BigB[k][512+p] = ML/MR[p][k] = sum_d Wc[p'][dofs+d] * W2[d][k]
__global__ void k_gemm_M(const float* __restrict__ W2, const float* __restrict__ Wc,
                         float* __restrict__ BigB) {
    __shared__ float W2s[32][33];
    __shared__ float Wcs[32][33];
    int ftile = blockIdx.x & 15;
    int ptile = blockIdx.x >> 4;          // 0..31 over p in [0,1024)
    int f0 = ftile*32, p0 = ptile*32;
    int dofs  = (p0 >= 512) ? 512 : 0;
    int prow0 = (p0 >= 512) ? (p0 - 512) : p0;
    int t = threadIdx.x;
    int ff = t & 31, pg = t >> 5;         // pg 0..7
    float acc[4] = {0,0,0,0};
    for (int d0 = 0; d0 < 512; d0 += 32) {
        __syncthreads();
        #pragma unroll
        for (int i = 0; i < 4; ++i) {
            int e = t + 256*i;
            int r = e >> 5, cc = e & 31;
            W2s[r][cc] = W2[(d0 + r)*512 + f0 + cc];
            Wcs[r][cc] = Wc[(prow0 + r)*1024 + dofs + d0 + cc];
        }
        __syncthreads();
        #pragma unroll
        for (int dd = 0; dd < 32; ++dd) {
            float w = W2s[dd][ff];
            #pragma unroll
            for (int ii = 0; ii < 4; ++ii)
                acc[ii] += w * Wcs[pg*4 + ii][dd];
        }
    }
    #pragma unroll
    for (int ii = 0; ii < 4; ++ii) {
        int p = p0 + pg*4 + ii;
        BigB[(f0 + ff)*1536 + 512 + p] = acc[ii];
    }
}

// BigB[k][c] f32 -> fragment-major bf16 hi/lo: fi = (c>>4)*8192 + (k>>3)*128 + (c&15)*8 + (k&7)
__global__ void k_makeBT(const float* __restrict__ BigB,
                         unsigned short* __restrict__ BTfH, unsigned short* __restrict__ BTfL) {
    int gid = blockIdx.x*256 + threadIdx.x;   // 1536*512 = 786432
    int c = gid >> 9, k = gid & 511;
    float v = BigB[k*1536 + c];
    unsigned short h = f2bf(v);
    unsigned short lo = f2bf(v - bf2f(h));
    size_t fi = (size_t)(c >> 4)*8192 + (k >> 3)*128 + (c & 15)*8 + (k & 7);
    BTfH[fi] = h; BTfL[fi] = lo;
}

// ---------------- level-0 vector GEMM: (32 x 512) @ (512 x NCOLS) ----------------
// MODE 0: diag   A=xs_h[cell]          B=W1T  bias=b1      -> table[i,i]
// MODE 1: pq0    A=table[(i,i)]        B=B0   bias=null    -> P,Q of level-0 cells
template<int MODE, int NCOLS>
__global__ __launch_bounds__(256) void k_gemm(
    const float* __restrict__ Abase, const float* __restrict__ Bmat,
    const float* __restrict__ bias,
    float* __restrict__ table, float* __restrict__ P, float* __restrict__ Q, int s)
{
    constexpr int CTILES = NCOLS / 256;
    int cell = blockIdx.x / CTILES;
    int ct   = blockIdx.x % CTILES;
    int c0   = ct * 256;
    const float* A;
    if (MODE == 0)      A = Abase + cell*CELLSZ;
    else                A = Abase + (size_t)cell*65*CELLSZ;

    __shared__ float Ast[32][36];     // A transposed: Ast[kk][r]
    __shared__ float Bs[32][256];
    int t  = threadIdx.x;
    int tx = t & 63, ty = t >> 6;     // cols 4*tx, rows 8*ty
    float acc[8][4];
    #pragma unroll
    for (int i = 0; i < 8; ++i)
        #pragma unroll
        for (int j = 0; j < 4; ++j) acc[i][j] = 0.f;

    for (int k0 = 0; k0 < 512; k0 += 32) {
        __syncthreads();
        {   // stage A (32 rows x 32 k), transposed into LDS
            int r = t >> 3, c4 = t & 7;
            float4 v = *reinterpret_cast<const float4*>(&A[r*512 + k0 + 4*c4]);
            Ast[4*c4+0][r] = v.x; Ast[4*c4+1][r] = v.y;
            Ast[4*c4+2][r] = v.z; Ast[4*c4+3][r] = v.w;
        }
        {   // stage B (32 k x 256 cols)
            int c4 = t & 63;
            int kbase = t >> 6;
            #pragma unroll
            for (int p = 0; p < 8; ++p) {
                int kk = p*4 + kbase;
                float4 v = *reinterpret_cast<const float4*>(&Bmat[(size_t)(k0+kk)*NCOLS + c0 + 4*c4]);
                *reinterpret_cast<float4*>(&Bs[kk][4*c4]) = v;
            }
        }
        __syncthreads();
        #pragma unroll
        for (int kk = 0; kk < 32; ++kk) {
            float4 a0 = *reinterpret_cast<const float4*>(&Ast[kk][8*ty]);
            float4 a1 = *reinterpret_cast<const float4*>(&Ast[kk][8*ty+4]);
            float4 b  = *reinterpret_cast<const float4*>(&Bs[kk][4*tx]);
            float av[8] = {a0.x,a0.y,a0.z,a0.w,a1.x,a1.y,a1.z,a1.w};
            #pragma unroll
            for (int i = 0; i < 8; ++i) {
                acc[i][0] += av[i]*b.x; acc[i][1] += av[i]*b.y;
                acc[i][2] += av[i]*b.z; acc[i][3] += av[i]*b.w;
            }
        }
    }
    #pragma unroll
    for (int i = 0; i < 8; ++i) {
        int r = 8*ty + i;
        int C = c0 + 4*tx;
        float4 v = make_float4(acc[i][0],acc[i][1],acc[i][2],acc[i][3]);
        if (MODE == 0) { v.x += bias[C]; v.y += bias[C+1]; v.z += bias[C+2]; v.w += bias[C+3]; }
        float* dst;
        if (MODE == 0) {
            dst = table + (size_t)cell*65*CELLSZ + r*512 + C;
        } else {
            int tc = tri_idx(cell, cell);
            dst = (C < 512) ? (P + (size_t)tc*CELLSZ + r*512 + C)
                            : (Q + (size_t)tc*CELLSZ + r*512 + (C - 512));
        }
        *reinterpret_cast<float4*>(dst) = v;
    }
}

// ---------------- per-level MFMA GEMM: (32 x 512) @ (512 x 1536), bf16x3 ----------------
// A = node (fragment-major bf16 hi/lo), B = BTf (fragment-major bf16 hi/lo)
// block = 256 thr = 4 waves; block tile 32 x 256; wave tile 32 x 64 (2x4 frags of 16x16)
__global__ __launch_bounds__(256) void k_gemm_mfma(
    const unsigned short* __restrict__ nodeH, const unsigned short* __restrict__ nodeL,
    const unsigned short* __restrict__ BTfH, const unsigned short* __restrict__ BTfL,
    const float* __restrict__ biasBig,
    float* __restrict__ table, float* __restrict__ P, float* __restrict__ Q, int s)
{
    int cell = blockIdx.x / 6;
    int ct   = blockIdx.x % 6;
    int t = threadIdx.x;
    int w = t >> 6, l = t & 63;
    int l15 = l & 15, lg = l >> 4;
    int c0 = ct*256 + w*64;

    f32x4 acc[2][4];
    #pragma unroll
    for (int i = 0; i < 2; ++i)
        #pragma unroll
        for (int j = 0; j < 4; ++j) acc[i][j] = (f32x4){0.f,0.f,0.f,0.f};

    size_t lane_off = (size_t)lg*128 + l15*8;
    const unsigned short* aH = nodeH + (size_t)cell*16384 + lane_off;
    const unsigned short* aL = nodeL + (size_t)cell*16384 + lane_off;
    const unsigned short* bH = BTfH + (size_t)(c0 >> 4)*8192 + lane_off;
    const unsigned short* bL = BTfL + (size_t)(c0 >> 4)*8192 + lane_off;

    #pragma unroll 2
    for (int ks = 0; ks < 16; ++ks) {
        int ko = ks * 512;       // 4 kg * 128 ushorts per k-step
        short8v ah0 = *(const short8v*)(aH + ko);
        short8v ah1 = *(const short8v*)(aH + ko + 8192);
        short8v al0 = *(const short8v*)(aL + ko);
        short8v al1 = *(const short8v*)(aL + ko + 8192);
        short8v bh[4], bl[4];
        #pragma unroll
        for (int cf = 0; cf < 4; ++cf) {
            bh[cf] = *(const short8v*)(bH + ko + cf*8192);
            bl[cf] = *(const short8v*)(bL + ko + cf*8192);
        }
        #pragma unroll
        for (int cf = 0; cf < 4; ++cf) {
            acc[0][cf] = __builtin_amdgcn_mfma_f32_16x16x32_bf16(ah0, bh[cf], acc[0][cf], 0, 0, 0);
            acc[1][cf] = __builtin_amdgcn_mfma_f32_16x16x32_bf16(ah1, bh[cf], acc[1][cf], 0, 0, 0);
            acc[0][cf] = __builtin_amdgcn_mfma_f32_16x16x32_bf16(al0, bh[cf], acc[0][cf], 0, 0, 0);
            acc[1][cf] = __builtin_amdgcn_mfma_f32_16x16x32_bf16(al1, bh[cf], acc[1][cf], 0, 0, 0);
            acc[0][cf] = __builtin_amdgcn_mfma_f32_16x16x32_bf16(ah0, bl[cf], acc[0][cf], 0, 0, 0);
            acc[1][cf] = __builtin_amdgcn_mfma_f32_16x16x32_bf16(ah1, bl[cf], acc[1][cf], 0, 0, 0);
        }
    }

    // epilogue: D row = rb*16 + lg*4 + j, col = c0 + cf*16 + l15
    int tc = tri_idx(cell, cell) + s;            // tri index of (cell, cell+s)
    size_t tblCell = (size_t)(cell*64 + cell + s)*CELLSZ;
    #pragma unroll
    for (int cf = 0; cf < 4; ++cf) {
        int c = c0 + cf*16 + l15;
        float bias = biasBig[c];
        float* base;
        int cc;
        if (c < 512)       { base = table + tblCell;          cc = c; }
        else if (c < 1024) { base = P + (size_t)tc*CELLSZ;    cc = c - 512; }
        else               { base = Q + (size_t)tc*CELLSZ;    cc = c - 1024; }
        #pragma unroll
        for (int rb = 0; rb < 2; ++rb) {
            #pragma unroll
            for (int j = 0; j < 4; ++j) {
                int r = rb*16 + lg*4 + j;
                base[(size_t)r*512 + cc] = acc[rb][cf][j] + bias;
            }
        }
    }
}

// ---------------- node max-reduce (writes bf16 hi/lo in fragment-major layout) ----------------
template<int BS>
__global__ __launch_bounds__(256) void k_node(const float* __restrict__ P,
                                              const float* __restrict__ Q,
                                              const float* __restrict__ bc,
                                              unsigned short* __restrict__ nodeH,
                                              unsigned short* __restrict__ nodeL, int s)
{
    constexpr int BPC = 4 * (32 / BS);          // blocks per cell
    constexpr int E = BS / 2;                   // elems per thread
    int j   = blockIdx.x / BPC;
    int sub = blockIdx.x % BPC;
    int fb = sub & 3, bh = sub >> 2;
    int t = threadIdx.x;
    int f = fb*128 + (t & 127);
    int b0 = bh*BS + (t >> 7);                  // + 2*e below
    float acc[E];
    #pragma unroll
    for (int e = 0; e < E; ++e) acc[e] = -3.402823466e38f;
    int basePt = tri_idx(j, j);
    for (int k = 0; k < s; ++k) {
        const float* Pp = P + (size_t)(basePt + k)*CELLSZ + f;
        int a = j + k + 1;
        int tQ = a*Lx - (a*(a-1))/2 + (j + s - a);
        const float* Qp = Q + (size_t)tQ*CELLSZ + f;
        #pragma unroll
        for (int e = 0; e < E; ++e) {
            int b = b0 + 2*e;
            float v = Pp[b*512] + Qp[b*512];
            acc[e] = fmaxf(acc[e], v);
        }
    }
    float bcv = bc[f];
    #pragma unroll
    for (int e = 0; e < E; ++e) {
        int b = b0 + 2*e;
        float v = acc[e] + bcv;
        unsigned short h = f2bf(v);
        unsigned short lo = f2bf(v - bf2f(h));
        size_t fi = (size_t)j*16384 + (size_t)(b >> 4)*8192 + (f >> 3)*128 + (b & 15)*8 + (f & 7);
        nodeH[fi] = h;
        nodeL[fi] = lo;
    }
}

// ---------------- launch ----------------

extern "C" void kernel_launch(void* const* d_in, const int* in_sizes, int n_in,
                              void* d_out, int out_size, void* d_ws, size_t ws_size,
                              hipStream_t stream) {
    const float* xs_h    = (const float*)d_in[0];
    const float* xs_mask = (const float*)d_in[1];
    const float* W1      = (const float*)d_in[2];
    const float* b1      = (const float*)d_in[3];
    const float* Wc      = (const float*)d_in[4];
    const float* bc      = (const float*)d_in[5];
    const float* W2      = (const float*)d_in[6];
    const float* b2      = (const float*)d_in[7];

    float* table   = (float*)d_out;                     // 64*64*32*512
    float* maskout = table + 67108864;                  // 64*64*32

    float* ws      = (float*)d_ws;
    float* P       = ws;                                // 34,078,720 floats
    float* Q       = P + 34078720;                      // 34,078,720
    unsigned short* nodeH = (unsigned short*)(Q + 34078720);   // 63*16384 ushorts
    unsigned short* nodeL = nodeH + 1032192;
    float* W1T     = (float*)(nodeL + 1032192);         // 512*512
    float* B0      = W1T + 262144;                      // 512*1024
    float* BigB    = B0 + 524288;                       // 512*1536
    unsigned short* BTfH = (unsigned short*)(BigB + 786432);   // 1536*512 ushorts
    unsigned short* BTfL = BTfH + 786432;
    float* biasBig = (float*)(BTfL + 786432);           // 1536
    float* lengths = biasBig + 1536;                    // 32

    hipMemsetAsync(table, 0, (size_t)67108864*4, stream);
    k_lengths<<<1, 64, 0, stream>>>(xs_mask, lengths);
    k_mask<<<512, 256, 0, stream>>>(lengths, maskout);
    k_transposes<<<4096, 256, 0, stream>>>(W1, W2, Wc, W1T, BigB, B0);
    k_gemm_M<<<512, 256, 0, stream>>>(W2, Wc, BigB);
    k_bias<<<6, 256, 0, stream>>>(b2, Wc, biasBig);
    k_makeBT<<<3072, 256, 0, stream>>>(BigB, BTfH, BTfL);

    // level 0: diag then P/Q projections (vector f32)
    k_gemm<0, 512><<<64*2, 256, 0, stream>>>(xs_h, W1T, b1, table, P, Q, 0);
    k_gemm<1, 1024><<<64*4, 256, 0, stream>>>(table, B0, nullptr, table, P, Q, 0);

    for (int s = 1; s < 64; ++s) {
        int n = 64 - s;
        if (n >= 16) k_node<16><<<n*8,  256, 0, stream>>>(P, Q, bc, nodeH, nodeL, s);
        else         k_node<2> <<<n*64, 256, 0, stream>>>(P, Q, bc, nodeH, nodeL, s);
        k_gemm_mfma<<<n*6, 256, 0, stream>>>(nodeH, nodeL, BTfH, BTfL, biasBig, table, P, Q, s);
    }
}

// Round 3
// 2426.121 us; speedup vs baseline: 1.6917x; 1.0287x over previous
//
#include <hip/hip_runtime.h>
#include <hip/hip_fp16.h>

// CYK net: L=64, B=32, DIN=D=FFS=512
//   P[cell] = table[cell] @ WcL.T ; Q[cell] = table[cell] @ WcR.T      (stored fp16)
//   node(j,s) = bc + max_k ( P[j,j+k] + Q[j+k+1,j+s] )                 (stored bf16 hi/lo, frag-major)
//   [vals|P|Q] = node @ BigB + biasBig   (one bf16x3 MFMA GEMM per level)

#define Lx 64
#define Bb 32
#define CELLSZ (Bb*512)         // 16384 elems per cell tile

typedef __attribute__((ext_vector_type(8))) short short8v;
typedef __attribute__((ext_vector_type(4))) float f32x4;

__device__ __forceinline__ int tri_idx(int a, int c) {
    return a*Lx - (a*(a-1))/2 + (c - a);
}
__device__ __forceinline__ unsigned short f2bf(float x) {
    unsigned u = __float_as_uint(x);
    unsigned r = (u + 0x7FFFu + ((u >> 16) & 1u)) >> 16;
    return (unsigned short)r;
}
__device__ __forceinline__ float bf2f(unsigned short h) {
    return __uint_as_float((unsigned)h << 16);
}
// fragment-major index for (row r, col/k c) pairs: A-style (r=row of 16-blk) or B-style (r=col)
__device__ __forceinline__ size_t frag_i(int r, int c) {
    return (size_t)(r >> 4)*8192 + (c >> 3)*128 + (r & 15)*8 + (c & 7);
}

// ---------------- setup kernels ----------------

__global__ void k_zero_lower(float* __restrict__ table) {
    int cell = blockIdx.x >> 4;          // 0..4095
    int i = cell >> 6, j = cell & 63;
    if (j >= i) return;                  // only strictly-lower cells need zeros
    int sub = blockIdx.x & 15;
    float4* p = (float4*)(table + (size_t)cell*CELLSZ) + sub*256 + threadIdx.x;
    *p = make_float4(0.f,0.f,0.f,0.f);
}

__global__ void k_lengths(const float* __restrict__ xs_mask, float* __restrict__ lengths) {
    int b = threadIdx.x;
    if (b < Bb) {
        float s = 0.f;
        for (int i = 0; i < Lx; ++i) s += xs_mask[i*Bb + b];
        lengths[b] = s;
    }
}

__global__ void k_mask(const float* __restrict__ lengths, float* __restrict__ mask_out) {
    int idx = blockIdx.x*256 + threadIdx.x;     // 64*64*32
    int b = idx & 31;
    int j = (idx >> 5) & 63;
    int i = idx >> 11;
    mask_out[idx] = (j >= i && (float)j < lengths[b]) ? 1.f : 0.f;
}

// biasBig = [ b2 | b2@WcL.T | b2@WcR.T ]
__global__ void k_bias(const float* __restrict__ b2, const float* __restrict__ Wc,
                       float* __restrict__ biasBig) {
    int c = blockIdx.x*256 + threadIdx.x;
    if (c >= 1536) return;
    if (c < 512) { biasBig[c] = b2[c]; return; }
    int p = (c - 512) & 511;
    int dofs = (c < 1024) ? 0 : 512;
    float s = 0.f;
    for (int d = 0; d < 512; ++d) s += b2[d] * Wc[p*1024 + dofs + d];
    biasBig[c] = s;
}

// xs_h (cell-major 32x512 f32) -> frag-major bf16 hi/lo
__global__ void k_prep_xh(const float* __restrict__ xs_h,
                          unsigned short* __restrict__ xhH, unsigned short* __restrict__ xhL) {
    int gid = blockIdx.x*256 + threadIdx.x;     // 64*16384
    int cell = gid >> 14, e = gid & 16383;
    int b = e >> 9, d = e & 511;
    float v = xs_h[gid];
    unsigned short h = f2bf(v);
    size_t fi = (size_t)cell*16384 + frag_i(b, d);
    xhH[fi] = h; xhL[fi] = f2bf(v - bf2f(h));
}

// W1 (DxDIN) -> B-frag-major hi/lo (col=output d, k=din): value = W1[c][k]
__global__ void k_prep_w1(const float* __restrict__ W1,
                          unsigned short* __restrict__ WH, unsigned short* __restrict__ WL) {
    int gid = blockIdx.x*256 + threadIdx.x;     // 512*512
    int c = gid >> 9, k = gid & 511;
    float v = W1[c*512 + k];
    unsigned short h = f2bf(v);
    size_t fi = frag_i(c, k);
    WH[fi] = h; WL[fi] = f2bf(v - bf2f(h));
}

// Wc -> B0 frag-major hi/lo: cols 0..511 = WcL.T, 512..1023 = WcR.T
__global__ void k_prep_b0(const float* __restrict__ Wc,
                          unsigned short* __restrict__ BH, unsigned short* __restrict__ BL) {
    int gid = blockIdx.x*256 + threadIdx.x;     // 1024*512
    int c = gid >> 9, k = gid & 511;
    float v = (c < 512) ? Wc[c*1024 + k] : Wc[(c-512)*1024 + 512 + k];
    unsigned short h = f2bf(v);
    size_t fi = frag_i(c, k);
    BH[fi] = h; BL[fi] = f2bf(v - bf2f(h));
}

// BigB[k][512+p] = sum_d Wc[p'][dofs+d] * W2[d][k]   (ML^T / MR^T, f32 staging)
__global__ void k_gemm_M(const float* __restrict__ W2, const float* __restrict__ Wc,
                         float* __restrict__ BigB) {
    __shared__ float W2s[32][33];
    __shared__ float Wcs[32][33];
    int ftile = blockIdx.x & 15;
    int ptile = blockIdx.x >> 4;
    int f0 = ftile*32, p0 = ptile*32;
    int dofs  = (p0 >= 512) ? 512 : 0;
    int prow0 = (p0 >= 512) ? (p0 - 512) : p0;
    int t = threadIdx.x;
    int ff = t & 31, pg = t >> 5;
    float acc[4] = {0,0,0,0};
    for (int d0 = 0; d0 < 512; d0 += 32) {
        __syncthreads();
        #pragma unroll
        for (int i = 0; i < 4; ++i) {
            int e = t + 256*i;
            int r = e >> 5, cc = e & 31;
            W2s[r][cc] = W2[(d0 + r)*512 + f0 + cc];
            Wcs[r][cc] = Wc[(prow0 + r)*1024 + dofs + d0 + cc];
        }
        __syncthreads();
        #pragma unroll
        for (int dd = 0; dd < 32; ++dd) {
            float w = W2s[dd][ff];
            #pragma unroll
            for (int ii = 0; ii < 4; ++ii)
                acc[ii] += w * Wcs[pg*4 + ii][dd];
        }
    }
    #pragma unroll
    for (int ii = 0; ii < 4; ++ii)
        BigB[(f0 + ff)*1536 + 512 + p0 + pg*4 + ii] = acc[ii];
}

// BigB cols -> frag-major bf16 hi/lo (cols<512 read W2 directly)
__global__ void k_makeBT(const float* __restrict__ W2, const float* __restrict__ BigB,
                         unsigned short* __restrict__ BTfH, unsigned short* __restrict__ BTfL) {
    int gid = blockIdx.x*256 + threadIdx.x;   // 1536*512
    int c = gid >> 9, k = gid & 511;
    float v = (c < 512) ? W2[c*512 + k] : BigB[k*1536 + c];
    unsigned short h = f2bf(v);
    size_t fi = frag_i(c, k);
    BTfH[fi] = h; BTfL[fi] = f2bf(v - bf2f(h));
}

// ---------------- unified MFMA GEMM: (32 x 512) @ (512 x NCOLS), bf16x3 ----------------
// MODE 0: A=xs_h frag  B=W1f  bias=b1      -> table diag f32 + diag frag hi/lo
// MODE 1: A=diag frag  B=B0f  (no bias)    -> P,Q fp16 at tri(i,i)
// MODE 2: A=node frag  B=BTf  bias=biasBig -> table[j,j+s] f32, P,Q fp16 at tri(j,j)+s
template<int MODE, int NCOLS>
__global__ __launch_bounds__(256) void k_mfma(
    const unsigned short* __restrict__ AH, const unsigned short* __restrict__ AL,
    const unsigned short* __restrict__ BH, const unsigned short* __restrict__ BL,
    const float* __restrict__ bias,
    float* __restrict__ table, __half* __restrict__ P, __half* __restrict__ Q,
    unsigned short* __restrict__ outH, unsigned short* __restrict__ outL, int s)
{
    constexpr int CTILES = NCOLS / 256;
    int cell = blockIdx.x / CTILES;
    int ct   = blockIdx.x % CTILES;
    int t = threadIdx.x;
    int w = t >> 6, l = t & 63;
    int l15 = l & 15, lg = l >> 4;
    int c0 = ct*256 + w*64;

    f32x4 acc[2][4];
    #pragma unroll
    for (int i = 0; i < 2; ++i)
        #pragma unroll
        for (int j = 0; j < 4; ++j) acc[i][j] = (f32x4){0.f,0.f,0.f,0.f};

    size_t lane_off = (size_t)lg*128 + l15*8;
    const unsigned short* aH = AH + (size_t)cell*16384 + lane_off;
    const unsigned short* aL = AL + (size_t)cell*16384 + lane_off;
    const unsigned short* bH = BH + (size_t)(c0 >> 4)*8192 + lane_off;
    const unsigned short* bL = BL + (size_t)(c0 >> 4)*8192 + lane_off;

    #pragma unroll 2
    for (int ks = 0; ks < 16; ++ks) {
        int ko = ks * 512;
        short8v ah0 = *(const short8v*)(aH + ko);
        short8v ah1 = *(const short8v*)(aH + ko + 8192);
        short8v al0 = *(const short8v*)(aL + ko);
        short8v al1 = *(const short8v*)(aL + ko + 8192);
        short8v bh[4], bl[4];
        #pragma unroll
        for (int cf = 0; cf < 4; ++cf) {
            bh[cf] = *(const short8v*)(bH + ko + cf*8192);
            bl[cf] = *(const short8v*)(bL + ko + cf*8192);
        }
        #pragma unroll
        for (int cf = 0; cf < 4; ++cf) {
            acc[0][cf] = __builtin_amdgcn_mfma_f32_16x16x32_bf16(ah0, bh[cf], acc[0][cf], 0, 0, 0);
            acc[1][cf] = __builtin_amdgcn_mfma_f32_16x16x32_bf16(ah1, bh[cf], acc[1][cf], 0, 0, 0);
            acc[0][cf] = __builtin_amdgcn_mfma_f32_16x16x32_bf16(al0, bh[cf], acc[0][cf], 0, 0, 0);
            acc[1][cf] = __builtin_amdgcn_mfma_f32_16x16x32_bf16(al1, bh[cf], acc[1][cf], 0, 0, 0);
            acc[0][cf] = __builtin_amdgcn_mfma_f32_16x16x32_bf16(ah0, bl[cf], acc[0][cf], 0, 0, 0);
            acc[1][cf] = __builtin_amdgcn_mfma_f32_16x16x32_bf16(ah1, bl[cf], acc[1][cf], 0, 0, 0);
        }
    }

    // epilogue: D row = rb*16 + lg*4 + j, col = c0 + cf*16 + l15
    #pragma unroll
    for (int cf = 0; cf < 4; ++cf) {
        int c = c0 + cf*16 + l15;
        if (MODE == 0) {
            float bv = bias[c];
            size_t tbl = (size_t)(cell*65)*CELLSZ;
            #pragma unroll
            for (int rb = 0; rb < 2; ++rb)
                #pragma unroll
                for (int j = 0; j < 4; ++j) {
                    int r = rb*16 + lg*4 + j;
                    float v = acc[rb][cf][j] + bv;
                    table[tbl + (size_t)r*512 + c] = v;
                    size_t fi = (size_t)cell*16384 + frag_i(r, c);
                    unsigned short h = f2bf(v);
                    outH[fi] = h; outL[fi] = f2bf(v - bf2f(h));
                }
        } else if (MODE == 1) {
            int tc = tri_idx(cell, cell);
            __half* dst = (c < 512) ? (P + (size_t)tc*CELLSZ) : (Q + (size_t)tc*CELLSZ);
            int cc = c & 511;
            #pragma unroll
            for (int rb = 0; rb < 2; ++rb)
                #pragma unroll
                for (int j = 0; j < 4; ++j) {
                    int r = rb*16 + lg*4 + j;
                    dst[(size_t)r*512 + cc] = __float2half(acc[rb][cf][j]);
                }
        } else {
            float bv = bias[c];
            int tc = tri_idx(cell, cell) + s;
            size_t tbl = (size_t)(cell*64 + cell + s)*CELLSZ;
            #pragma unroll
            for (int rb = 0; rb < 2; ++rb)
                #pragma unroll
                for (int j = 0; j < 4; ++j) {
                    int r = rb*16 + lg*4 + j;
                    float v = acc[rb][cf][j] + bv;
                    if (c < 512)       table[tbl + (size_t)r*512 + c] = v;
                    else if (c < 1024) P[(size_t)tc*CELLSZ + (size_t)r*512 + (c-512)]  = __float2half(v);
                    else               Q[(size_t)tc*CELLSZ + (size_t)r*512 + (c-1024)] = __float2half(v);
                }
        }
    }
}

// ---------------- node max-reduce: fp16 P/Q in, bf16 hi/lo frag-major out ----------------
// MAIN: block covers 128 f x 16 b, BPC = 8.  TAIL: 128 f x 4 b, BPC = 32.
template<int TAIL>
__global__ __launch_bounds__(256) void k_node(const __half* __restrict__ P,
                                              const __half* __restrict__ Q,
                                              const float* __restrict__ bc,
                                              unsigned short* __restrict__ nodeH,
                                              unsigned short* __restrict__ nodeL, int s)
{
    constexpr int BPC = TAIL ? 32 : 8;
    constexpr int E   = TAIL ? 1 : 4;
    int j   = blockIdx.x / BPC;
    int sub = blockIdx.x % BPC;
    int fb  = sub & 3;
    int bq  = sub >> 2;                       // 0..1 (main) or 0..7 (tail)
    int t = threadIdx.x;
    int f = fb*128 + 2*(t & 63);
    int bl = t >> 6;                          // 0..3
    int bbase = TAIL ? (bq*4 + bl) : (bq*16 + bl);
    float2 acc[E];
    #pragma unroll
    for (int e = 0; e < E; ++e) acc[e] = make_float2(-3.4e38f, -3.4e38f);

    int basePt = tri_idx(j, j);
    for (int k = 0; k < s; ++k) {
        const __half* Pp = P + (size_t)(basePt + k)*CELLSZ + f;
        int a = j + k + 1;
        int tQ = a*Lx - (a*(a-1))/2 + (j + s - a);
        const __half* Qp = Q + (size_t)tQ*CELLSZ + f;
        #pragma unroll
        for (int e = 0; e < E; ++e) {
            int b = bbase + 4*e;
            float2 vp = __half22float2(*(const __half2*)(Pp + (size_t)b*512));
            float2 vq = __half22float2(*(const __half2*)(Qp + (size_t)b*512));
            acc[e].x = fmaxf(acc[e].x, vp.x + vq.x);
            acc[e].y = fmaxf(acc[e].y, vp.y + vq.y);
        }
    }
    float bc0 = bc[f], bc1 = bc[f+1];
    #pragma unroll
    for (int e = 0; e < E; ++e) {
        int b = bbase + 4*e;
        float v0 = acc[e].x + bc0;
        float v1 = acc[e].y + bc1;
        unsigned short h0 = f2bf(v0), h1 = f2bf(v1);
        unsigned short l0 = f2bf(v0 - bf2f(h0)), l1 = f2bf(v1 - bf2f(h1));
        size_t fi = (size_t)j*16384 + frag_i(b, f);
        *(unsigned*)(nodeH + fi) = (unsigned)h0 | ((unsigned)h1 << 16);
        *(unsigned*)(nodeL + fi) = (unsigned)l0 | ((unsigned)l1 << 16);
    }
}

// ---------------- launch ----------------

extern "C" void kernel_launch(void* const* d_in, const int* in_sizes, int n_in,
                              void* d_out, int out_size, void* d_ws, size_t ws_size,
                              hipStream_t stream) {
    const float* xs_h    = (const float*)d_in[0];
    const float* xs_mask = (const float*)d_in[1];
    const float* W1      = (const float*)d_in[2];
    const float* b1      = (const float*)d_in[3];
    const float* Wc      = (const float*)d_in[4];
    const float* bc      = (const float*)d_in[5];
    const float* W2      = (const float*)d_in[6];
    const float* b2      = (const float*)d_in[7];

    float* table   = (float*)d_out;                     // 64*64*32*512 f32
    float* maskout = table + 67108864;                  // 64*64*32

    __half* P = (__half*)d_ws;                          // 2080*16384 halves
    __half* Q = P + 34078720;
    unsigned short* nodeH = (unsigned short*)(Q + 34078720);   // 63*16384
    unsigned short* nodeL = nodeH + 1032192;
    unsigned short* xhH   = nodeL + 1032192;            // 64*16384
    unsigned short* xhL   = xhH + 1048576;
    unsigned short* diagH = xhL + 1048576;              // 64*16384
    unsigned short* diagL = diagH + 1048576;
    unsigned short* W1fH  = diagL + 1048576;            // 512*512
    unsigned short* W1fL  = W1fH + 262144;
    unsigned short* B0fH  = W1fL + 262144;              // 1024*512
    unsigned short* B0fL  = B0fH + 524288;
    unsigned short* BTfH  = B0fL + 524288;              // 1536*512
    unsigned short* BTfL  = BTfH + 786432;
    float* BigB    = (float*)(BTfL + 786432);           // 512*1536 f32 (cols 512+ used)
    float* biasBig = BigB + 786432;                     // 1536
    float* lengths = biasBig + 1536;                    // 32

    k_zero_lower<<<65536, 256, 0, stream>>>(table);
    k_lengths<<<1, 64, 0, stream>>>(xs_mask, lengths);
    k_mask<<<512, 256, 0, stream>>>(lengths, maskout);
    k_prep_xh<<<4096, 256, 0, stream>>>(xs_h, xhH, xhL);
    k_prep_w1<<<1024, 256, 0, stream>>>(W1, W1fH, W1fL);
    k_prep_b0<<<2048, 256, 0, stream>>>(Wc, B0fH, B0fL);
    k_gemm_M<<<512, 256, 0, stream>>>(W2, Wc, BigB);
    k_bias<<<6, 256, 0, stream>>>(b2, Wc, biasBig);
    k_makeBT<<<3072, 256, 0, stream>>>(W2, BigB, BTfH, BTfL);

    // level 0: diag (also emits frag-major diag), then P/Q projections
    k_mfma<0, 512><<<64*2, 256, 0, stream>>>(xhH, xhL, W1fH, W1fL, b1,
                                             table, nullptr, nullptr, diagH, diagL, 0);
    k_mfma<1, 1024><<<64*4, 256, 0, stream>>>(diagH, diagL, B0fH, B0fL, nullptr,
                                              table, P, Q, nullptr, nullptr, 0);

    for (int s = 1; s < 64; ++s) {
        int n = 64 - s;
        if (n >= 16) k_node<0><<<n*8,  256, 0, stream>>>(P, Q, bc, nodeH, nodeL, s);
        else         k_node<1><<<n*32, 256, 0, stream>>>(P, Q, bc, nodeH, nodeL, s);
        k_mfma<2, 1536><<<n*6, 256, 0, stream>>>(nodeH, nodeL, BTfH, BTfL, biasBig,
                                                 table, P, Q, nullptr, nullptr, s);
    }
}